// Round 6
// baseline (229.052 us; speedup 1.0000x reference)
//
#include <hip/hip_runtime.h>

// TT layer via bf16 MFMA (gfx950), NB=4 batches per WG, conflict-free LDS.
//   Phase A: z1[b][k'=m2*16+r][m3]  = core0[n1]^T . x[b]       (MFMA K=32)
//   Phase B: z2[b][k2=m3*16+s'][n2] = A1[512,512] . z1         (MFMA, K=512)
//            8 waves x (M=64 rows, N=128 cols) -> acc[4][8]
//   Phase C: y[b][n2,n3] = z2 . W2T^T + bias                   (MFMA K=512)
// LDS z-tile layout (32 KB per b): element (k 0..511, c 0..31) at byte
//   (k>>5)*2048 + c*64 + (((k&31)<<1) ^ ((c>>1&1)<<5))
// -> wave b128 reads cover 64 distinct 16B slots (zero bank conflicts);
//    phase-A b64 writes also conflict-free (16 slots x 4 rows = minimum).
// XCD-swizzled blockIdx; d_ws (bf16): A1[(n2*16+s')][(m2*16+r)],
//   A0T[(n1*16+s)][m1], W2T[n3][(m3*16+s')], xT[b][p][m1].

typedef __attribute__((ext_vector_type(8))) short bf16x8;
typedef __attribute__((ext_vector_type(4))) float f32x4;

#define WS_A1   0
#define WS_A0T  262144
#define WS_W2T  278528
#define WS_XT   294912
#define WS_XT_ELEMS 8388608
#define WS_NEED_BYTES ((size_t)(WS_XT + WS_XT_ELEMS) * 2)

__device__ __forceinline__ unsigned short f2bf(float f) {
    union { float f; unsigned int u; } v; v.f = f;
    unsigned int u = v.u;
    u += 0x7fffu + ((u >> 16) & 1u);   // RNE (inputs finite)
    return (unsigned short)(u >> 16);
}

// ---------------- prep: core transforms (+ optional x transpose) ----------------
template<bool XT>
__global__ void tt_prep(const float* __restrict__ x,
                        const float* __restrict__ core0,
                        const float* __restrict__ core1,
                        const float* __restrict__ core2,
                        unsigned short* __restrict__ ws)
{
    const int t = threadIdx.x;
    if (XT && blockIdx.x < 8192) {
        // transpose x[b][m1][m2*32+m3] (f32) -> xT[b][p=m2*32+m3][m1] (bf16)
        __shared__ float tile[32 * 36];
        const int b  = blockIdx.x >> 5;
        const int m2 = blockIdx.x & 31;
        {
            const int m1 = t >> 3, c4 = (t & 7) * 4;
            float4 v = *(const float4*)(x + (size_t)b * 32768 + m1 * 1024 + m2 * 32 + c4);
            *(float4*)&tile[m1 * 36 + c4] = v;
        }
        __syncthreads();
        {
            const int m3 = t >> 3, g = t & 7;
            unsigned short o[4];
            #pragma unroll
            for (int j = 0; j < 4; ++j)
                o[j] = f2bf(tile[(g * 4 + j) * 36 + m3]);
            unsigned short* dst = ws + WS_XT + (size_t)b * 32768 + (m2 * 32 + m3) * 32 + g * 4;
            *(uint2*)dst = *(uint2*)o;
        }
        return;
    }
    const int u = (blockIdx.x - (XT ? 8192 : 0)) * 256 + t;
    unsigned short* A1  = ws + WS_A1;    // [512 rows=(n2*16+s')][512 cols=(m2*16+r)]
    unsigned short* A0T = ws + WS_A0T;   // [512 rows=(n1*16+s)][32 m1]
    unsigned short* W2T = ws + WS_W2T;   // [32 n3][512 k2=(m3*16+s')]
    bf16x8 o;
    if (u < 32768) {
        int e = u * 8;
        int row = e >> 9, col0 = e & 511;
        int n2 = row >> 4, s = row & 15;
        int m2 = col0 >> 4, r0 = col0 & 15;   // r0 in {0,8}
        const float* src = core1 + n2 * 512 + m2 * 16 + s;
        #pragma unroll
        for (int j = 0; j < 8; ++j) o[j] = (short)f2bf(src[(r0 + j) * 16384]);
        *(bf16x8*)(A1 + e) = o;
    } else if (u < 34816) {
        int e = (u - 32768) * 8;
        int row = e >> 5, m1b = e & 31;    // row = n1*16 + s
        int n1 = row >> 4, s = row & 15;
        const float* src = core0 + n1 * 512 + m1b * 16 + s;
        #pragma unroll
        for (int j = 0; j < 8; ++j) o[j] = (short)f2bf(src[j * 16]);
        *(bf16x8*)(A0T + e) = o;
    } else if (u < 36864) {
        int e = (u - 34816) * 8;
        int n3 = e >> 9, k20 = e & 511;
        int m3 = k20 >> 4, s0 = k20 & 15;  // s0 in {0,8}
        const float* src = core2 + n3 * 32 + m3;
        #pragma unroll
        for (int j = 0; j < 8; ++j) o[j] = (short)f2bf(src[(s0 + j) * 1024]);
        *(bf16x8*)(W2T + e) = o;
    }
}

// ---------------- main fused kernel ----------------
template<bool XT>
__global__ __launch_bounds__(512, 2)
void tt_mfma(const float* __restrict__ x,
             const unsigned short* __restrict__ ws,
             const float* __restrict__ bias,
             float* __restrict__ out)
{
    extern __shared__ char smem[];   // 4 x 32KB: z-tile per local b

    const unsigned short* A1  = ws + WS_A1;
    const unsigned short* A0T = ws + WS_A0T;
    const unsigned short* W2T = ws + WS_W2T;
    const unsigned short* xT  = ws + WS_XT;

    const int t   = threadIdx.x;
    const int l   = t & 63;
    const int w   = t >> 6;        // wave 0..7
    const int l15 = l & 15;
    const int lg  = l >> 4;        // 0..3

    // XCD-aware bijective swizzle: 2048 WGs, 8 XCDs, 256 per XCD.
    const int swzid = (blockIdx.x & 7) * 256 + (blockIdx.x >> 3);
    const int bq = swzid >> 5;
    const int n1 = swzid & 31;

    // common swizzle term for reads: bit5 ^= (c>>1)&1 with c = l15-varying row
    const int swz5 = ((l15 >> 1) & 1) << 5;

    // ---- Phase A: wave -> (lb = w>>1, p-half = w&1); 32 MFMAs, dbuf'd ----
    {
        const int lb = w >> 1, ph = w & 1;
        const int b  = bq * 4 + lb;
        char* zb = smem + lb * 32768;
        bf16x8 afrag = *(const bf16x8*)(A0T + n1 * 512 + l15 * 32 + lg * 8);
        if (XT) {
            const unsigned short* xb = xT + (size_t)b * 32768 + lg * 8;
            bf16x8 bfrag[2];
            bfrag[0] = *(const bf16x8*)(xb + (ph * 512 + l15) * 32);
            #pragma unroll
            for (int pti = 0; pti < 32; ++pti) {
                if (pti < 31) {
                    int pn = ph * 512 + (pti + 1) * 16 + l15;
                    bfrag[(pti + 1) & 1] = *(const bf16x8*)(xb + pn * 32);
                }
                int p = ph * 512 + pti * 16 + l15;
                f32x4 c = __builtin_amdgcn_mfma_f32_16x16x32_bf16(
                    afrag, bfrag[pti & 1], (f32x4){0.f, 0.f, 0.f, 0.f}, 0, 0, 0);
                int m2 = p >> 5, m3 = p & 31;
                unsigned short h[4];
                #pragma unroll
                for (int i = 0; i < 4; ++i) h[i] = f2bf(c[i]);
                // k' = m2*16 + (lg*4+i): chunk = m2>>1, within = (m2&1)*32+lg*8
                int off = ((m2 >> 1) << 11) + (m3 << 6) +
                          ((((m2 & 1) << 5) + (lg << 3)) ^ (((m3 >> 1) & 1) << 5));
                *(uint2*)(zb + off) = *(uint2*)h;
            }
        } else {
            const float* xb = x + (size_t)b * 32768 + (lg * 8) * 1024;
            for (int pti = 0; pti < 32; ++pti) {
                int p = ph * 512 + pti * 16 + l15;
                bf16x8 bfrag;
                #pragma unroll
                for (int j = 0; j < 8; ++j) bfrag[j] = (short)f2bf(xb[j * 1024 + p]);
                f32x4 c = __builtin_amdgcn_mfma_f32_16x16x32_bf16(
                    afrag, bfrag, (f32x4){0.f, 0.f, 0.f, 0.f}, 0, 0, 0);
                int m2 = p >> 5, m3 = p & 31;
                unsigned short h[4];
                #pragma unroll
                for (int i = 0; i < 4; ++i) h[i] = f2bf(c[i]);
                int off = ((m2 >> 1) << 11) + (m3 << 6) +
                          ((((m2 & 1) << 5) + (lg << 3)) ^ (((m3 >> 1) & 1) << 5));
                *(uint2*)(zb + off) = *(uint2*)h;
            }
        }
    }
    __syncthreads();

    // ---- Phase B: wave w owns M rows [w*64, w*64+64); N = 128 (4 b x 32 m3) ----
    f32x4 acc[4][8];
    #pragma unroll
    for (int mt = 0; mt < 4; ++mt)
        #pragma unroll
        for (int nt = 0; nt < 8; ++nt)
            acc[mt][nt] = (f32x4){0.f, 0.f, 0.f, 0.f};
    {
        const unsigned short* a1p = A1 + (w * 64 + l15) * 512 + lg * 8;
        const int kofs = (lg << 4) ^ swz5;        // within-chunk byte for reads
        const int rlo = (l15 << 6) + kofs;        // m3 = l15
        const int rhi = rlo + 1024;               // m3 = 16 + l15

        bf16x8 af[2][4], bf[2][8];
        #pragma unroll
        for (int mt = 0; mt < 4; ++mt)
            af[0][mt] = *(const bf16x8*)(a1p + mt * 8192);
        #pragma unroll
        for (int b4 = 0; b4 < 4; ++b4) {
            char* zb = smem + b4 * 32768;
            bf[0][b4 * 2 + 0] = *(const bf16x8*)(zb + rlo);
            bf[0][b4 * 2 + 1] = *(const bf16x8*)(zb + rhi);
        }
        #pragma unroll
        for (int ks = 0; ks < 16; ++ks) {
            const int cur = ks & 1, nxt = cur ^ 1;
            if (ks < 15) {
                #pragma unroll
                for (int mt = 0; mt < 4; ++mt)
                    af[nxt][mt] = *(const bf16x8*)(a1p + mt * 8192 + (ks + 1) * 32);
                #pragma unroll
                for (int b4 = 0; b4 < 4; ++b4) {
                    char* zb = smem + b4 * 32768 + (ks + 1) * 2048;
                    bf[nxt][b4 * 2 + 0] = *(const bf16x8*)(zb + rlo);
                    bf[nxt][b4 * 2 + 1] = *(const bf16x8*)(zb + rhi);
                }
            }
            __builtin_amdgcn_s_setprio(1);
            #pragma unroll
            for (int mt = 0; mt < 4; ++mt)
                #pragma unroll
                for (int nt = 0; nt < 8; ++nt)
                    acc[mt][nt] = __builtin_amdgcn_mfma_f32_16x16x32_bf16(
                        af[cur][mt], bf[cur][nt], acc[mt][nt], 0, 0, 0);
            __builtin_amdgcn_s_setprio(0);
        }
    }
    __syncthreads();   // all z1 reads complete

    // write z2 (bf16): element (k2 = m3*16 + s', n2); s' = lg*4+i -> b64 stores
    {
        #pragma unroll
        for (int mt = 0; mt < 4; ++mt) {
            int n2 = w * 4 + mt;
            int nsw = ((n2 >> 1) & 1) << 5;
            #pragma unroll
            for (int nt = 0; nt < 8; ++nt) {
                char* zb = smem + (nt >> 1) * 32768;
                int m3 = (nt & 1) * 16 + l15;
                unsigned short h[4];
                #pragma unroll
                for (int i = 0; i < 4; ++i) h[i] = f2bf(acc[mt][nt][i]);
                // chunk = m3>>1, within = (m3&1)*32 + lg*8, row byte = n2*64
                int off = ((m3 >> 1) << 11) + (n2 << 6) +
                          ((((m3 & 1) << 5) + (lg << 3)) ^ nsw);
                *(uint2*)(zb + off) = *(uint2*)h;
            }
        }
    }
    __syncthreads();

    // ---- Phase C: wave -> (lb = w>>1, n3-half = w&1); y = z2 . W2T^T + bias ----
    {
        const int lb = w >> 1, n3h = w & 1;
        const int b  = bq * 4 + lb;
        char* zb = smem + lb * 32768;
        f32x4 c[2];
        c[0] = (f32x4){0.f, 0.f, 0.f, 0.f};
        c[1] = (f32x4){0.f, 0.f, 0.f, 0.f};
        const unsigned short* w2p = W2T + (n3h * 16 + l15) * 512 + lg * 8;
        const int kofs = (lg << 4) ^ swz5;
        bf16x8 bfg[2];
        bfg[0] = *(const bf16x8*)(w2p);
        #pragma unroll
        for (int ks = 0; ks < 16; ++ks) {
            if (ks < 15) bfg[(ks + 1) & 1] = *(const bf16x8*)(w2p + (ks + 1) * 32);
            #pragma unroll
            for (int mt = 0; mt < 2; ++mt) {
                int n2 = mt * 16 + l15;
                bf16x8 af = *(const bf16x8*)(zb + ks * 2048 + (n2 << 6) + kofs);
                c[mt] = __builtin_amdgcn_mfma_f32_16x16x32_bf16(af, bfg[ks & 1], c[mt], 0, 0, 0);
            }
        }
        int n3 = n3h * 16 + l15;
        size_t ob = (size_t)b * 32768 + (size_t)n1 * 1024;
        const float* bp2 = bias + n1 * 1024;
        #pragma unroll
        for (int mt = 0; mt < 2; ++mt)
            #pragma unroll
            for (int i = 0; i < 4; ++i) {
                int n2 = mt * 16 + lg * 4 + i;
                out[ob + n2 * 32 + n3] = c[mt][i] + bp2[n2 * 32 + n3];
            }
    }
}

extern "C" void kernel_launch(void* const* d_in, const int* in_sizes, int n_in,
                              void* d_out, int out_size, void* d_ws, size_t ws_size,
                              hipStream_t stream) {
    (void)in_sizes; (void)n_in; (void)out_size;
    const float* x     = (const float*)d_in[0];
    const float* core0 = (const float*)d_in[1];
    const float* core1 = (const float*)d_in[2];
    const float* core2 = (const float*)d_in[3];
    const float* bias  = (const float*)d_in[4];
    float* out = (float*)d_out;
    unsigned short* ws = (unsigned short*)d_ws;

    const int lds_bytes = 4 * 32768;   // 128 KB
    if (ws_size >= WS_NEED_BYTES) {
        hipFuncSetAttribute((const void*)tt_mfma<true>,
                            hipFuncAttributeMaxDynamicSharedMemorySize, lds_bytes);
        tt_prep<true><<<8336, 256, 0, stream>>>(x, core0, core1, core2, ws);
        tt_mfma<true><<<2048, 512, lds_bytes, stream>>>(x, ws, bias, out);
    } else {
        hipFuncSetAttribute((const void*)tt_mfma<false>,
                            hipFuncAttributeMaxDynamicSharedMemorySize, lds_bytes);
        tt_prep<false><<<144, 256, 0, stream>>>(x, core0, core1, core2, ws);
        tt_mfma<false><<<2048, 512, lds_bytes, stream>>>(x, ws, bias, out);
    }
}